// Round 3
// baseline (120615.991 us; speedup 1.0000x reference)
//
#include <hip/hip_runtime.h>

// MogLSTM T=1024, B=64, H=512, 2 layers, 5 mog steps.
// 4 independent batch row-groups (16 rows each); per group: 64 WGs
// (2 layers x 32 col-slices of 16), layer-pipelined, 6 phases/superstep,
// private group barrier (slots -> master poll -> broadcast), spin-capped.
// Weights+activations in hi/lo fp16 split (fp32-accurate), c-state fp32 regs.
// All scratch in __device__ globals; d_ws unused.

#define T_LEN 1024
#define BB 64
#define HH 512
#define NG 4
#define GWG 64
#define NWG (NG * GWG)
#define RPG 16
#define SPIN_CAP 2000000

typedef __attribute__((ext_vector_type(8))) _Float16 f16x8;
typedef __attribute__((ext_vector_type(4))) float f32x4;

#define MW_N (2 * 5 * 512 * 512)
#define GW_N (2 * 2048 * 512)
#define ACT_N (2 * 64 * 512)

__device__ _Float16 g_mw_hi[MW_N];
__device__ _Float16 g_mw_lo[MW_N];
__device__ _Float16 g_wih_hi[GW_N];
__device__ _Float16 g_wih_lo[GW_N];
__device__ _Float16 g_whh_hi[GW_N];
__device__ _Float16 g_whh_lo[GW_N];
__device__ _Float16 g_xb_hi[ACT_N], g_xb_lo[ACT_N];
__device__ _Float16 g_hm_hi[ACT_N], g_hm_lo[ACT_N];
__device__ _Float16 g_hs_hi[ACT_N], g_hs_lo[ACT_N];
__device__ int g_slots[NWG * 32];   // padded: one 128B line per WG
__device__ int g_bcast[NG * 32];    // one padded broadcast word per group

__device__ __forceinline__ float sigmoidf_(float z) {
    return 1.f / (1.f + expf(-z));
}
__device__ __forceinline__ float tanhf_(float z) {
    float a = fabsf(z);
    float e = expf(-2.f * a);
    float t = (1.f - e) / (1.f + e);
    return z >= 0.f ? t : -t;
}
__device__ __forceinline__ void split_store(_Float16* hi, _Float16* lo, int idx, float v) {
    _Float16 h = (_Float16)v;
    hi[idx] = h;
    lo[idx] = (_Float16)(v - (float)h);
}

__global__ void prep_kernel(const float* __restrict__ mogW,
                            const float* __restrict__ Wih,
                            const float* __restrict__ Whh) {
    size_t tid = (size_t)blockIdx.x * blockDim.x + threadIdx.x;
    size_t gs = (size_t)gridDim.x * blockDim.x;
    for (size_t i = tid; i < MW_N; i += gs) {
        float w = mogW[i];
        _Float16 h = (_Float16)w;
        g_mw_hi[i] = h;
        g_mw_lo[i] = (_Float16)(w - (float)h);
    }
    for (size_t i = tid; i < GW_N; i += gs) {
        float w = Wih[i];
        _Float16 h = (_Float16)w;
        g_wih_hi[i] = h;
        g_wih_lo[i] = (_Float16)(w - (float)h);
        w = Whh[i];
        h = (_Float16)w;
        g_whh_hi[i] = h;
        g_whh_lo[i] = (_Float16)(w - (float)h);
    }
    for (size_t i = tid; i < ACT_N; i += gs) {
        g_xb_hi[i] = (_Float16)0.f; g_xb_lo[i] = (_Float16)0.f;
        g_hm_hi[i] = (_Float16)0.f; g_hm_lo[i] = (_Float16)0.f;
        g_hs_hi[i] = (_Float16)0.f; g_hs_lo[i] = (_Float16)0.f;
    }
    for (size_t i = tid; i < NWG * 32; i += gs) g_slots[i] = 0;
    for (size_t i = tid; i < NG * 32; i += gs) g_bcast[i] = 0;
}

// Group barrier. 1 wave per WG. Arrive: lane0 release-store to padded slot.
// Master WG: 64 lanes poll 64 slots 1:1, then lane0 release-stores broadcast.
// Everyone polls broadcast, then acquire-fence. Spin caps keep us alive on bugs.
__device__ __forceinline__ void gbarrier(int g, int u6, bool master, int phase, bool* dead) {
    const int lane = threadIdx.x;
    if (lane == 0) {
        __hip_atomic_store(&g_slots[(g * GWG + u6) * 32], phase,
                           __ATOMIC_RELEASE, __HIP_MEMORY_SCOPE_AGENT);
    }
    if (*dead) return;
    if (master) {
        int* p = &g_slots[(g * GWG + lane) * 32];
        int guard = 0;
        while (__hip_atomic_load(p, __ATOMIC_RELAXED, __HIP_MEMORY_SCOPE_AGENT) < phase) {
            if (++guard > SPIN_CAP) { *dead = true; break; }
            __builtin_amdgcn_s_sleep(2);
        }
        if (lane == 0) {
            __hip_atomic_store(&g_bcast[g * 32], phase,
                               __ATOMIC_RELEASE, __HIP_MEMORY_SCOPE_AGENT);
        }
    }
    {
        int* p = &g_bcast[g * 32];
        int guard = 0;
        while (__hip_atomic_load(p, __ATOMIC_RELAXED, __HIP_MEMORY_SCOPE_AGENT) < phase) {
            if (++guard > SPIN_CAP) { *dead = true; break; }
            __builtin_amdgcn_s_sleep(2);
        }
        __builtin_amdgcn_fence(__ATOMIC_ACQUIRE, "agent");
    }
}

// [16x16] output tile over K=512, hi/lo 3-term MFMA. Pointers pre-offset to
// (row*HH + ah*8); stride 32 halfs per k-block.
__device__ __forceinline__ f32x4 mm16(const _Float16* a_hi, const _Float16* a_lo,
                                      const _Float16* b_hi, const _Float16* b_lo) {
    f32x4 e = {0.f, 0.f, 0.f, 0.f};
    f32x4 o = {0.f, 0.f, 0.f, 0.f};
#pragma unroll
    for (int kb = 0; kb < 16; kb += 2) {
        f16x8 ah0 = *(const f16x8*)(a_hi + kb * 32);
        f16x8 al0 = *(const f16x8*)(a_lo + kb * 32);
        f16x8 bh0 = *(const f16x8*)(b_hi + kb * 32);
        f16x8 bl0 = *(const f16x8*)(b_lo + kb * 32);
        e = __builtin_amdgcn_mfma_f32_16x16x32_f16(ah0, bh0, e, 0, 0, 0);
        e = __builtin_amdgcn_mfma_f32_16x16x32_f16(ah0, bl0, e, 0, 0, 0);
        e = __builtin_amdgcn_mfma_f32_16x16x32_f16(al0, bh0, e, 0, 0, 0);
        f16x8 ah1 = *(const f16x8*)(a_hi + (kb + 1) * 32);
        f16x8 al1 = *(const f16x8*)(a_lo + (kb + 1) * 32);
        f16x8 bh1 = *(const f16x8*)(b_hi + (kb + 1) * 32);
        f16x8 bl1 = *(const f16x8*)(b_lo + (kb + 1) * 32);
        o = __builtin_amdgcn_mfma_f32_16x16x32_f16(ah1, bh1, o, 0, 0, 0);
        o = __builtin_amdgcn_mfma_f32_16x16x32_f16(ah1, bl1, o, 0, 0, 0);
        o = __builtin_amdgcn_mfma_f32_16x16x32_f16(al1, bh1, o, 0, 0, 0);
    }
    return e + o;
}

__global__ __launch_bounds__(64) void moglstm_kernel(
    const float* __restrict__ input_seq,   // [T][B][H]
    const float* __restrict__ mogb,        // [2][5][H]
    const float* __restrict__ b_ih,        // [2][4H]
    const float* __restrict__ b_hh,        // [2][4H]
    float* __restrict__ out)               // outputs | last_h | last_c
{
    const int wg = blockIdx.x;
    const int g = wg >> 6;          // row-group 0..3 (rows g*16..g*16+15)
    const int u6 = wg & 63;
    const int l = u6 >> 5;          // layer 0/1 (pipelined)
    const int c = u6 & 31;          // col-slice (16 cols); XCD = c%8
    const bool master = (u6 == 0);
    const int lane = threadIdx.x;
    const int al = lane & 15;
    const int ah = lane >> 4;
    const int r0 = g * RPG;

    const int mcol = c * 16 + al;             // mog output col for this lane
    const size_t aoff = (size_t)(r0 + al) * HH + ah * 8;  // A-operand offset
    const int lb = l * BB * HH;               // per-layer act base

    _Float16* xbh = g_xb_hi + lb; _Float16* xbl = g_xb_lo + lb;
    _Float16* hmh = g_hm_hi + lb; _Float16* hml = g_hm_lo + lb;
    _Float16* hsh = g_hs_hi + lb; _Float16* hsl = g_hs_lo + lb;

    // biases: per-lane constants
    float mbias[5];
#pragma unroll
    for (int m = 0; m < 5; ++m) mbias[m] = mogb[(l * 5 + m) * HH + mcol];
    const int jc = c * 16 + al;   // gate col for this lane
    const float bgi = b_ih[l*4*HH + 0*HH + jc] + b_hh[l*4*HH + 0*HH + jc];
    const float bgf = b_ih[l*4*HH + 1*HH + jc] + b_hh[l*4*HH + 1*HH + jc];
    const float bgg = b_ih[l*4*HH + 2*HH + jc] + b_hh[l*4*HH + 2*HH + jc];
    const float bgo = b_ih[l*4*HH + 3*HH + jc] + b_hh[l*4*HH + 3*HH + jc];

    // weight pointers (pre-offset per lane)
    const size_t wrow = (size_t)(c * 16 + al) * HH + ah * 8;
    const _Float16* mwh[5]; const _Float16* mwl[5];
#pragma unroll
    for (int m = 0; m < 5; ++m) {
        size_t base = (size_t)(l * 5 + m) * HH * HH;
        mwh[m] = g_mw_hi + base + wrow;
        mwl[m] = g_mw_lo + base + wrow;
    }
    const _Float16* gih[4]; const _Float16* gil[4];
    const _Float16* ghh[4]; const _Float16* ghl[4];
#pragma unroll
    for (int gi = 0; gi < 4; ++gi) {
        size_t base = ((size_t)l * 4 * HH + gi * HH) * HH + wrow;
        gih[gi] = g_wih_hi + base; gil[gi] = g_wih_lo + base;
        ghh[gi] = g_whh_hi + base; ghl[gi] = g_whh_lo + base;
    }

    float c_reg[4] = {0.f, 0.f, 0.f, 0.f};
    bool dead = false;
    int phase = 0;

    for (int s = 0; s <= T_LEN; ++s) {
        const int t = (l == 0) ? s : s - 1;
        const bool active = (t >= 0) && (t < T_LEN);

        // ---- 5 mogrifier stages ----
        for (int m = 0; m < 5; ++m) {
            if (active) {
                const _Float16 *mvh, *mvl;   // matmul operand
                const _Float16 *ueh, *uel;   // elementwise operand
                _Float16 *dh, *dl;           // destination
                switch (m) {
                    case 0:  mvh = hsh; mvl = hsl; ueh = nullptr; uel = nullptr; dh = xbh; dl = xbl; break;
                    case 1:  mvh = xbh; mvl = xbl; ueh = hsh; uel = hsl; dh = hmh; dl = hml; break;
                    case 2:  mvh = hmh; mvl = hml; ueh = xbh; uel = xbl; dh = xbh; dl = xbl; break;
                    case 3:  mvh = xbh; mvl = xbl; ueh = hmh; uel = hml; dh = hmh; dl = hml; break;
                    default: mvh = hmh; mvl = hml; ueh = xbh; uel = xbl; dh = xbh; dl = xbl; break;
                }
                f32x4 acc = mm16(mvh + aoff, mvl + aoff, mwh[m], mwl[m]);
#pragma unroll
                for (int r = 0; r < 4; ++r) {
                    int row = r0 + ah * 4 + r;
                    int idx = row * HH + mcol;
                    float z = acc[r] + mbias[m];
                    float sg = 2.f * sigmoidf_(z);
                    float u;
                    if (m == 0) {
                        if (l == 0)
                            u = input_seq[(size_t)t * BB * HH + idx];
                        else
                            u = (float)g_hs_hi[idx] + (float)g_hs_lo[idx];  // h1(t)
                    } else {
                        u = (float)ueh[idx] + (float)uel[idx];
                    }
                    split_store(dh, dl, idx, sg * u);
                }
            }
            gbarrier(g, u6, master, ++phase, &dead);
        }

        // ---- gates + LSTM update ----
        if (active) {
            f32x4 acc[4];
#pragma unroll
            for (int gi = 0; gi < 4; ++gi) acc[gi] = (f32x4){0.f, 0.f, 0.f, 0.f};

            const _Float16* axh = xbh + aoff;  const _Float16* axl = xbl + aoff;
            const _Float16* amh = hmh + aoff;  const _Float16* aml = hml + aoff;
#pragma unroll
            for (int kb = 0; kb < 16; ++kb) {
                f16x8 xh = *(const f16x8*)(axh + kb * 32);
                f16x8 xl = *(const f16x8*)(axl + kb * 32);
#pragma unroll
                for (int gi = 0; gi < 4; ++gi) {
                    f16x8 bh = *(const f16x8*)(gih[gi] + kb * 32);
                    f16x8 bl = *(const f16x8*)(gil[gi] + kb * 32);
                    acc[gi] = __builtin_amdgcn_mfma_f32_16x16x32_f16(xh, bh, acc[gi], 0, 0, 0);
                    acc[gi] = __builtin_amdgcn_mfma_f32_16x16x32_f16(xh, bl, acc[gi], 0, 0, 0);
                    acc[gi] = __builtin_amdgcn_mfma_f32_16x16x32_f16(xl, bh, acc[gi], 0, 0, 0);
                }
            }
#pragma unroll
            for (int kb = 0; kb < 16; ++kb) {
                f16x8 xh = *(const f16x8*)(amh + kb * 32);
                f16x8 xl = *(const f16x8*)(aml + kb * 32);
#pragma unroll
                for (int gi = 0; gi < 4; ++gi) {
                    f16x8 bh = *(const f16x8*)(ghh[gi] + kb * 32);
                    f16x8 bl = *(const f16x8*)(ghl[gi] + kb * 32);
                    acc[gi] = __builtin_amdgcn_mfma_f32_16x16x32_f16(xh, bh, acc[gi], 0, 0, 0);
                    acc[gi] = __builtin_amdgcn_mfma_f32_16x16x32_f16(xh, bl, acc[gi], 0, 0, 0);
                    acc[gi] = __builtin_amdgcn_mfma_f32_16x16x32_f16(xl, bh, acc[gi], 0, 0, 0);
                }
            }
#pragma unroll
            for (int r = 0; r < 4; ++r) {
                int row = r0 + ah * 4 + r;
                int idx = row * HH + jc;
                float ig = sigmoidf_(acc[0][r] + bgi);
                float fg = sigmoidf_(acc[1][r] + bgf);
                float gg = tanhf_(acc[2][r] + bgg);
                float og = sigmoidf_(acc[3][r] + bgo);
                float cc = fg * c_reg[r] + ig * gg;
                c_reg[r] = cc;
                float h = og * tanhf_(cc);
                split_store(hsh, hsl, idx, h);
                if (l == 1)
                    out[(size_t)t * BB * HH + idx] = h;
                if (t == T_LEN - 1) {
                    out[(size_t)T_LEN * BB * HH + (size_t)l * BB * HH + idx] = h;
                    out[(size_t)T_LEN * BB * HH + 2u * BB * HH + (size_t)l * BB * HH + idx] = cc;
                }
            }
        }
        gbarrier(g, u6, master, ++phase, &dead);
    }
}

extern "C" void kernel_launch(void* const* d_in, const int* in_sizes, int n_in,
                              void* d_out, int out_size, void* d_ws, size_t ws_size,
                              hipStream_t stream) {
    const float* input_seq = (const float*)d_in[0];
    const float* mogW = (const float*)d_in[1];
    const float* mogb = (const float*)d_in[2];
    const float* W_ih = (const float*)d_in[3];
    const float* W_hh = (const float*)d_in[4];
    const float* b_ih = (const float*)d_in[5];
    const float* b_hh = (const float*)d_in[6];
    float* out = (float*)d_out;
    (void)d_ws; (void)ws_size;

    hipLaunchKernelGGL(prep_kernel, dim3(1024), dim3(256), 0, stream,
                       mogW, W_ih, W_hh);
    hipLaunchKernelGGL(moglstm_kernel, dim3(NWG), dim3(64), 0, stream,
                       input_seq, mogb, b_ih, b_hh, out);
}